// Round 1
// baseline (1652.759 us; speedup 1.0000x reference)
//
#include <hip/hip_runtime.h>

#define LRELU(x) ((x) >= 0.0f ? (x) : 0.2f * (x))

// ---------------------------------------------------------------------------
// K1: node attention tables: fc = feat@W_prop, as = feat@W_attn_src,
//     ad = feat@W_attn_dst   (each [N,8])
// Thread t -> (node n = gid>>3, head h = gid&7). Weights staged in LDS (24KB).
// ---------------------------------------------------------------------------
__global__ __launch_bounds__(256) void k_node_tables(
    const float* __restrict__ feat,
    const float* __restrict__ Wp, const float* __restrict__ Was,
    const float* __restrict__ Wad,
    float* __restrict__ fc, float* __restrict__ as_t, float* __restrict__ ad_t,
    int N)
{
    __shared__ float Wl[3 * 2048];  // 3 x [256][8]
    for (int i = threadIdx.x; i < 3 * 2048; i += 256) {
        float v;
        if (i < 2048)      v = Wp[i];
        else if (i < 4096) v = Was[i - 2048];
        else               v = Wad[i - 4096];
        Wl[i] = v;
    }
    __syncthreads();
    int gid = blockIdx.x * 256 + threadIdx.x;
    int n = gid >> 3, h = gid & 7;
    if (n >= N) return;
    const float4* f4 = (const float4*)(feat + (size_t)n * 256);
    float aP = 0.f, aS = 0.f, aD = 0.f;
#pragma unroll 8
    for (int k4 = 0; k4 < 64; ++k4) {
        float4 f = f4[k4];
        int b = k4 * 32 + h;  // (k4*4)*8 + h
        aP += f.x * Wl[b]        + f.y * Wl[b + 8]        + f.z * Wl[b + 16]        + f.w * Wl[b + 24];
        aS += f.x * Wl[2048 + b] + f.y * Wl[2048 + b + 8] + f.z * Wl[2048 + b + 16] + f.w * Wl[2048 + b + 24];
        aD += f.x * Wl[4096 + b] + f.y * Wl[4096 + b + 8] + f.z * Wl[4096 + b + 16] + f.w * Wl[4096 + b + 24];
    }
    fc[gid] = aP; as_t[gid] = aS; ad_t[gid] = aD;
}

// ---------------------------------------------------------------------------
// Edge kernels: 8 threads per edge (lane group = one edge, lane%8 = head).
// No segment-max: e is bounded (~|e|<25), exp(e) safe in fp32.
// ---------------------------------------------------------------------------
__device__ __forceinline__ float edge_ex(
    const float* __restrict__ feat_edge, const float* Wl,
    const float* __restrict__ as_t, const float* __restrict__ ad_t,
    int e, int h, int s, int d)
{
    const float4* fe = (const float4*)(feat_edge + (size_t)e * 16);
    float4 f0 = fe[0], f1 = fe[1], f2 = fe[2], f3 = fe[3];
    float ae = f0.x * Wl[h]      + f0.y * Wl[h + 8]   + f0.z * Wl[h + 16]  + f0.w * Wl[h + 24]
             + f1.x * Wl[h + 32] + f1.y * Wl[h + 40]  + f1.z * Wl[h + 48]  + f1.w * Wl[h + 56]
             + f2.x * Wl[h + 64] + f2.y * Wl[h + 72]  + f2.z * Wl[h + 80]  + f2.w * Wl[h + 88]
             + f3.x * Wl[h + 96] + f3.y * Wl[h + 104] + f3.z * Wl[h + 112] + f3.w * Wl[h + 120];
    float ev = as_t[s * 8 + h] + ad_t[d * 8 + h] + ae;
    ev = LRELU(ev);
    return __expf(ev);
}

__global__ __launch_bounds__(256) void k_edge1(
    const float* __restrict__ feat_edge,
    const int* __restrict__ src, const int* __restrict__ dst,
    const float* __restrict__ We,
    const float* __restrict__ as_t, const float* __restrict__ ad_t,
    float* __restrict__ sum_dst, float* __restrict__ sum_src, int E)
{
    __shared__ float Wl[128];
    if (threadIdx.x < 128) Wl[threadIdx.x] = We[threadIdx.x];
    __syncthreads();
    int gid = blockIdx.x * 256 + threadIdx.x;
    int e = gid >> 3, h = gid & 7;
    if (e >= E) return;
    int s = src[e], d = dst[e];
    float ex = edge_ex(feat_edge, Wl, as_t, ad_t, e, h, s, d);
    atomicAdd(&sum_dst[d * 8 + h], ex);
    atomicAdd(&sum_src[s * 8 + h], ex);
}

__global__ __launch_bounds__(256) void k_edge2(
    const float* __restrict__ feat_edge,
    const int* __restrict__ src, const int* __restrict__ dst,
    const float* __restrict__ We,
    const float* __restrict__ as_t, const float* __restrict__ ad_t,
    const float* __restrict__ sum_dst, const float* __restrict__ sum_src,
    const float* __restrict__ fc, float* __restrict__ msg, int E)
{
    __shared__ float Wl[128];
    if (threadIdx.x < 128) Wl[threadIdx.x] = We[threadIdx.x];
    __syncthreads();
    int gid = blockIdx.x * 256 + threadIdx.x;
    int e = gid >> 3, h = gid & 7;
    if (e >= E) return;
    int s = src[e], d = dst[e];
    float ex = edge_ex(feat_edge, Wl, as_t, ad_t, e, h, s, d);
    float a_d = fmaxf(ex / sum_dst[d * 8 + h], 1e-9f);
    float a_s = fmaxf(ex / sum_src[s * 8 + h], 1e-9f);
    float a = sqrtf(a_d * a_s);
    atomicAdd(&msg[d * 8 + h], fc[s * 8 + h] * a);
}

// ---------------------------------------------------------------------------
// BatchNorm statistics: accum[0..7] = sum_h, accum[8..15] = sumsq_h
// ---------------------------------------------------------------------------
__global__ __launch_bounds__(256) void k_bn_stats(
    const float* __restrict__ msg, float* __restrict__ accum, int N)
{
    __shared__ float s1[8], s2[8];
    if (threadIdx.x < 8) { s1[threadIdx.x] = 0.f; s2[threadIdx.x] = 0.f; }
    __syncthreads();
    int h = threadIdx.x & 7;
    float a1 = 0.f, a2 = 0.f;
    int total = N * 8;
    for (int i = blockIdx.x * 256 + threadIdx.x; i < total; i += gridDim.x * 256) {
        float x = msg[i];  // i & 7 == h (strides are multiples of 8)
        a1 += x; a2 += x * x;
    }
    atomicAdd(&s1[h], a1);
    atomicAdd(&s2[h], a2);
    __syncthreads();
    if (threadIdx.x < 8) {
        atomicAdd(&accum[threadIdx.x], s1[threadIdx.x]);
        atomicAdd(&accum[8 + threadIdx.x], s2[threadIdx.x]);
    }
}

__global__ __launch_bounds__(256) void k_bn_apply(
    const float* __restrict__ msg, const float* __restrict__ accum,
    const float* __restrict__ gamma, const float* __restrict__ beta,
    float* __restrict__ h_t, int N)
{
    int i = blockIdx.x * 256 + threadIdx.x;
    if (i >= N * 8) return;
    int h = i & 7;
    float invN = 1.0f / (float)N;
    float mu = accum[h] * invN;
    float var = accum[8 + h] * invN - mu * mu;
    float rstd = rsqrtf(var + 1e-5f);
    h_t[i] = (msg[i] - mu) * rstd * gamma[h] + beta[h];
}

// ---------------------------------------------------------------------------
// GEMM 1: out[n][j] = leaky( feat[n]@W1[:,j] + h[n]@Wagg[:,j] + b_agg[j] + b1[j] )
// Block = 32 rows x all 256 cols. 256 threads, 4x8 micro-tile (cols strided 32).
// ---------------------------------------------------------------------------
__global__ __launch_bounds__(256) void k_apply1(
    const float* __restrict__ feat, const float* __restrict__ h_t,
    const float* __restrict__ W1, const float* __restrict__ Wagg,
    const float* __restrict__ b_agg, const float* __restrict__ b1,
    float* __restrict__ out, int N)
{
    __shared__ float As[32 * 256];
    __shared__ float Bs[16 * 256];
    __shared__ float Hs[32 * 8];
    __shared__ float Gs[8 * 256];
    int row0 = blockIdx.x * 32;
    // Stage A tile (32x256), h tile (32x8), Wagg (8x256)
    for (int i = threadIdx.x; i < 32 * 64; i += 256) {
        int r = i >> 6;
        if (row0 + r < N)
            ((float4*)As)[i] = ((const float4*)(feat + (size_t)row0 * 256))[i];
    }
    for (int i = threadIdx.x; i < 8 * 64; i += 256)
        ((float4*)Gs)[i] = ((const float4*)Wagg)[i];
    {
        int i = threadIdx.x;  // 256 = 32*8
        if (row0 + (i >> 3) < N) Hs[i] = h_t[row0 * 8 + i];
    }
    int tc = threadIdx.x & 31;
    int tr = threadIdx.x >> 5;
    float acc[4][8];
#pragma unroll
    for (int r = 0; r < 4; ++r)
#pragma unroll
        for (int c = 0; c < 8; ++c) acc[r][c] = 0.f;

    for (int kc = 0; kc < 16; ++kc) {
        __syncthreads();
        for (int i = threadIdx.x; i < 16 * 64; i += 256)
            ((float4*)Bs)[i] = ((const float4*)(W1 + (size_t)kc * 16 * 256))[i];
        __syncthreads();
#pragma unroll
        for (int kk = 0; kk < 16; kk += 4) {
            float4 av[4];
#pragma unroll
            for (int r = 0; r < 4; ++r)
                av[r] = *(const float4*)&As[(tr * 4 + r) * 256 + kc * 16 + kk];
#pragma unroll
            for (int j = 0; j < 4; ++j) {
                float a0 = ((const float*)&av[0])[j];
                float a1 = ((const float*)&av[1])[j];
                float a2 = ((const float*)&av[2])[j];
                float a3 = ((const float*)&av[3])[j];
#pragma unroll
                for (int c = 0; c < 8; ++c) {
                    float b = Bs[(kk + j) * 256 + tc + 32 * c];
                    acc[0][c] += a0 * b;
                    acc[1][c] += a1 * b;
                    acc[2][c] += a2 * b;
                    acc[3][c] += a3 * b;
                }
            }
        }
    }
    // Epilogue: + h@Wagg + biases, leaky
#pragma unroll
    for (int kh = 0; kh < 8; ++kh) {
        float hv[4];
#pragma unroll
        for (int r = 0; r < 4; ++r) hv[r] = Hs[(tr * 4 + r) * 8 + kh];
#pragma unroll
        for (int c = 0; c < 8; ++c) {
            float g = Gs[kh * 256 + tc + 32 * c];
#pragma unroll
            for (int r = 0; r < 4; ++r) acc[r][c] += hv[r] * g;
        }
    }
#pragma unroll
    for (int c = 0; c < 8; ++c) {
        int col = tc + 32 * c;
        float bb = b_agg[col] + b1[col];
#pragma unroll
        for (int r = 0; r < 4; ++r) {
            int row = row0 + tr * 4 + r;
            if (row < N) {
                float v = acc[r][c] + bb;
                out[(size_t)row * 256 + col] = LRELU(v);
            }
        }
    }
}

// ---------------------------------------------------------------------------
// GEMM 2 (in-place): io[n][j] = io[n]@W2[:,j] + b2[j]
// Safe in-place: each block owns rows [row0,row0+32) and covers all cols;
// the whole A tile is staged to LDS before any write.
// ---------------------------------------------------------------------------
__global__ __launch_bounds__(256) void k_apply2(
    float* __restrict__ io, const float* __restrict__ W2,
    const float* __restrict__ b2, int N)
{
    __shared__ float As[32 * 256];
    __shared__ float Bs[16 * 256];
    int row0 = blockIdx.x * 32;
    for (int i = threadIdx.x; i < 32 * 64; i += 256) {
        int r = i >> 6;
        if (row0 + r < N)
            ((float4*)As)[i] = ((const float4*)(io + (size_t)row0 * 256))[i];
    }
    int tc = threadIdx.x & 31;
    int tr = threadIdx.x >> 5;
    float acc[4][8];
#pragma unroll
    for (int r = 0; r < 4; ++r)
#pragma unroll
        for (int c = 0; c < 8; ++c) acc[r][c] = 0.f;

    for (int kc = 0; kc < 16; ++kc) {
        __syncthreads();
        for (int i = threadIdx.x; i < 16 * 64; i += 256)
            ((float4*)Bs)[i] = ((const float4*)(W2 + (size_t)kc * 16 * 256))[i];
        __syncthreads();
#pragma unroll
        for (int kk = 0; kk < 16; kk += 4) {
            float4 av[4];
#pragma unroll
            for (int r = 0; r < 4; ++r)
                av[r] = *(const float4*)&As[(tr * 4 + r) * 256 + kc * 16 + kk];
#pragma unroll
            for (int j = 0; j < 4; ++j) {
                float a0 = ((const float*)&av[0])[j];
                float a1 = ((const float*)&av[1])[j];
                float a2 = ((const float*)&av[2])[j];
                float a3 = ((const float*)&av[3])[j];
#pragma unroll
                for (int c = 0; c < 8; ++c) {
                    float b = Bs[(kk + j) * 256 + tc + 32 * c];
                    acc[0][c] += a0 * b;
                    acc[1][c] += a1 * b;
                    acc[2][c] += a2 * b;
                    acc[3][c] += a3 * b;
                }
            }
        }
    }
#pragma unroll
    for (int c = 0; c < 8; ++c) {
        int col = tc + 32 * c;
        float bb = b2[col];
#pragma unroll
        for (int r = 0; r < 4; ++r) {
            int row = row0 + tr * 4 + r;
            if (row < N)
                io[(size_t)row * 256 + col] = acc[r][c] + bb;
        }
    }
}

// ---------------------------------------------------------------------------
extern "C" void kernel_launch(void* const* d_in, const int* in_sizes, int n_in,
                              void* d_out, int out_size, void* d_ws, size_t ws_size,
                              hipStream_t stream)
{
    const float* feat      = (const float*)d_in[0];
    const float* feat_edge = (const float*)d_in[1];
    const int*   src       = (const int*)d_in[2];
    const int*   dst       = (const int*)d_in[3];
    const float* W_prop    = (const float*)d_in[4];
    const float* W_as      = (const float*)d_in[5];
    const float* W_ad      = (const float*)d_in[6];
    const float* W_edge    = (const float*)d_in[7];
    const float* bn_gamma  = (const float*)d_in[8];
    const float* bn_beta   = (const float*)d_in[9];
    const float* W_agg     = (const float*)d_in[10];
    const float* b_agg     = (const float*)d_in[11];
    const float* W1        = (const float*)d_in[12];
    const float* b1        = (const float*)d_in[13];
    const float* W2        = (const float*)d_in[14];
    const float* b2        = (const float*)d_in[15];
    float* out = (float*)d_out;

    int N = in_sizes[0] / 256;
    int E = in_sizes[2];
    int N8 = N * 8;

    // Workspace layout (floats): [sum_dst N8][sum_src N8][msg N8][accum 16]
    //                            [fc N8][as N8][ad N8][h N8]
    float* ws       = (float*)d_ws;
    float* sum_dst  = ws;
    float* sum_src  = sum_dst + N8;
    float* msg      = sum_src + N8;
    float* accum    = msg + N8;
    float* fc       = accum + 16;
    float* as_t     = fc + N8;
    float* ad_t     = as_t + N8;
    float* h_t      = ad_t + N8;

    // Zero the accumulated buffers (ws is poisoned 0xAA before every launch)
    hipMemsetAsync(d_ws, 0, (size_t)(3 * N8 + 16) * sizeof(float), stream);

    int gridN8 = (N8 + 255) / 256;
    int gridE8 = (E * 8 + 255) / 256;
    int gridM  = (N + 31) / 32;

    k_node_tables<<<gridN8, 256, 0, stream>>>(feat, W_prop, W_as, W_ad,
                                              fc, as_t, ad_t, N);
    k_edge1<<<gridE8, 256, 0, stream>>>(feat_edge, src, dst, W_edge,
                                        as_t, ad_t, sum_dst, sum_src, E);
    k_edge2<<<gridE8, 256, 0, stream>>>(feat_edge, src, dst, W_edge,
                                        as_t, ad_t, sum_dst, sum_src,
                                        fc, msg, E);
    k_bn_stats<<<512, 256, 0, stream>>>(msg, accum, N);
    k_bn_apply<<<gridN8, 256, 0, stream>>>(msg, accum, bn_gamma, bn_beta, h_t, N);
    k_apply1<<<gridM, 256, 0, stream>>>(feat, h_t, W1, W_agg, b_agg, b1, out, N);
    k_apply2<<<gridM, 256, 0, stream>>>(out, W2, b2, N);
}

// Round 2
// 1067.585 us; speedup vs baseline: 1.5481x; 1.5481x over previous
//
#include <hip/hip_runtime.h>

#define LRELU(x) ((x) >= 0.0f ? (x) : 0.2f * (x))

typedef __attribute__((ext_vector_type(8))) short short8;
typedef __attribute__((ext_vector_type(4))) float f32x4;

__device__ __forceinline__ unsigned short f2bf(float f) {
    union { float f; unsigned int u; } v; v.f = f;
    unsigned int u = v.u;
    u += 0x7FFFu + ((u >> 16) & 1u);   // round-to-nearest-even
    return (unsigned short)(u >> 16);
}

// ---------------------------------------------------------------------------
// K1: node attention tables: fc = feat@W_prop, as = feat@W_attn_src,
//     ad = feat@W_attn_dst   (each [N,8])
// ---------------------------------------------------------------------------
__global__ __launch_bounds__(256) void k_node_tables(
    const float* __restrict__ feat,
    const float* __restrict__ Wp, const float* __restrict__ Was,
    const float* __restrict__ Wad,
    float* __restrict__ fc, float* __restrict__ as_t, float* __restrict__ ad_t,
    int N)
{
    __shared__ float Wl[3 * 2048];  // 3 x [256][8]
    for (int i = threadIdx.x; i < 3 * 2048; i += 256) {
        float v;
        if (i < 2048)      v = Wp[i];
        else if (i < 4096) v = Was[i - 2048];
        else               v = Wad[i - 4096];
        Wl[i] = v;
    }
    __syncthreads();
    int gid = blockIdx.x * 256 + threadIdx.x;
    int n = gid >> 3, h = gid & 7;
    if (n >= N) return;
    const float4* f4 = (const float4*)(feat + (size_t)n * 256);
    float aP = 0.f, aS = 0.f, aD = 0.f;
#pragma unroll 8
    for (int k4 = 0; k4 < 64; ++k4) {
        float4 f = f4[k4];
        int b = k4 * 32 + h;
        aP += f.x * Wl[b]        + f.y * Wl[b + 8]        + f.z * Wl[b + 16]        + f.w * Wl[b + 24];
        aS += f.x * Wl[2048 + b] + f.y * Wl[2048 + b + 8] + f.z * Wl[2048 + b + 16] + f.w * Wl[2048 + b + 24];
        aD += f.x * Wl[4096 + b] + f.y * Wl[4096 + b + 8] + f.z * Wl[4096 + b + 16] + f.w * Wl[4096 + b + 24];
    }
    fc[gid] = aP; as_t[gid] = aS; ad_t[gid] = aD;
}

// ---------------------------------------------------------------------------
// Edge kernels: 8 threads per edge (lane group = one edge, lane%8 = head).
// No segment-max: e is bounded (~|e|<25), exp(e) safe in fp32.
// ---------------------------------------------------------------------------
__device__ __forceinline__ float edge_ex(
    const float* __restrict__ feat_edge, const float* Wl,
    const float* __restrict__ as_t, const float* __restrict__ ad_t,
    int e, int h, int s, int d)
{
    const float4* fe = (const float4*)(feat_edge + (size_t)e * 16);
    float4 f0 = fe[0], f1 = fe[1], f2 = fe[2], f3 = fe[3];
    float ae = f0.x * Wl[h]      + f0.y * Wl[h + 8]   + f0.z * Wl[h + 16]  + f0.w * Wl[h + 24]
             + f1.x * Wl[h + 32] + f1.y * Wl[h + 40]  + f1.z * Wl[h + 48]  + f1.w * Wl[h + 56]
             + f2.x * Wl[h + 64] + f2.y * Wl[h + 72]  + f2.z * Wl[h + 80]  + f2.w * Wl[h + 88]
             + f3.x * Wl[h + 96] + f3.y * Wl[h + 104] + f3.z * Wl[h + 112] + f3.w * Wl[h + 120];
    float ev = as_t[s * 8 + h] + ad_t[d * 8 + h] + ae;
    ev = LRELU(ev);
    return __expf(ev);
}

__global__ __launch_bounds__(256) void k_edge1(
    const float* __restrict__ feat_edge,
    const int* __restrict__ src, const int* __restrict__ dst,
    const float* __restrict__ We,
    const float* __restrict__ as_t, const float* __restrict__ ad_t,
    float* __restrict__ sum_dst, float* __restrict__ sum_src, int E)
{
    __shared__ float Wl[128];
    if (threadIdx.x < 128) Wl[threadIdx.x] = We[threadIdx.x];
    __syncthreads();
    int gid = blockIdx.x * 256 + threadIdx.x;
    int e = gid >> 3, h = gid & 7;
    if (e >= E) return;
    int s = src[e], d = dst[e];
    float ex = edge_ex(feat_edge, Wl, as_t, ad_t, e, h, s, d);
    atomicAdd(&sum_dst[d * 8 + h], ex);
    atomicAdd(&sum_src[s * 8 + h], ex);
}

__global__ __launch_bounds__(256) void k_edge2(
    const float* __restrict__ feat_edge,
    const int* __restrict__ src, const int* __restrict__ dst,
    const float* __restrict__ We,
    const float* __restrict__ as_t, const float* __restrict__ ad_t,
    const float* __restrict__ sum_dst, const float* __restrict__ sum_src,
    const float* __restrict__ fc, float* __restrict__ msg, int E)
{
    __shared__ float Wl[128];
    if (threadIdx.x < 128) Wl[threadIdx.x] = We[threadIdx.x];
    __syncthreads();
    int gid = blockIdx.x * 256 + threadIdx.x;
    int e = gid >> 3, h = gid & 7;
    if (e >= E) return;
    int s = src[e], d = dst[e];
    float ex = edge_ex(feat_edge, Wl, as_t, ad_t, e, h, s, d);
    float a_d = fmaxf(ex / sum_dst[d * 8 + h], 1e-9f);
    float a_s = fmaxf(ex / sum_src[s * 8 + h], 1e-9f);
    float a = sqrtf(a_d * a_s);
    atomicAdd(&msg[d * 8 + h], fc[s * 8 + h] * a);
}

// ---------------------------------------------------------------------------
// BatchNorm statistics: accum[0..7] = sum_h, accum[8..15] = sumsq_h
// ---------------------------------------------------------------------------
__global__ __launch_bounds__(256) void k_bn_stats(
    const float* __restrict__ msg, float* __restrict__ accum, int N)
{
    __shared__ float s1[8], s2[8];
    if (threadIdx.x < 8) { s1[threadIdx.x] = 0.f; s2[threadIdx.x] = 0.f; }
    __syncthreads();
    int h = threadIdx.x & 7;
    float a1 = 0.f, a2 = 0.f;
    int total = N * 8;
    for (int i = blockIdx.x * 256 + threadIdx.x; i < total; i += gridDim.x * 256) {
        float x = msg[i];
        a1 += x; a2 += x * x;
    }
    atomicAdd(&s1[h], a1);
    atomicAdd(&s2[h], a2);
    __syncthreads();
    if (threadIdx.x < 8) {
        atomicAdd(&accum[threadIdx.x], s1[threadIdx.x]);
        atomicAdd(&accum[8 + threadIdx.x], s2[threadIdx.x]);
    }
}

__global__ __launch_bounds__(256) void k_bn_apply(
    const float* __restrict__ msg, const float* __restrict__ accum,
    const float* __restrict__ gamma, const float* __restrict__ beta,
    float* __restrict__ h_t, int N)
{
    int i = blockIdx.x * 256 + threadIdx.x;
    if (i >= N * 8) return;
    int h = i & 7;
    float invN = 1.0f / (float)N;
    float mu = accum[h] * invN;
    float var = accum[8 + h] * invN - mu * mu;
    float rstd = rsqrtf(var + 1e-5f);
    h_t[i] = (msg[i] - mu) * rstd * gamma[h] + beta[h];
}

// ---------------------------------------------------------------------------
// Prep: bf16 weight tables in B-fragment layout [chunk][n:256][k:32]
//   B1t: chunks 0..7 = W1 (W_apply_dst), chunk 8 = [W_agg ; zeros]  (K=288)
//   B2t: chunks 0..7 = W2 (W_apply)                                  (K=256)
//   bias1[n] = b_agg[n] + b1[n];  bias2[n] = b2[n]
// ---------------------------------------------------------------------------
__global__ __launch_bounds__(256) void k_prep(
    const float* __restrict__ W1, const float* __restrict__ Wagg,
    const float* __restrict__ W2,
    const float* __restrict__ b_agg, const float* __restrict__ b1,
    const float* __restrict__ b2,
    unsigned short* __restrict__ B1t, unsigned short* __restrict__ B2t,
    float* __restrict__ bias1, float* __restrict__ bias2)
{
    int idx = blockIdx.x * 256 + threadIdx.x;
    if (idx < 73728) {                       // 9 chunks * 8192
        int c = idx >> 13, rem = idx & 8191;
        int n = rem >> 5, k = rem & 31;
        float v;
        if (c < 8) v = W1[(c * 32 + k) * 256 + n];
        else       v = (k < 8) ? Wagg[k * 256 + n] : 0.f;
        B1t[idx] = f2bf(v);
    } else if (idx < 139264) {               // + 8 chunks * 8192
        int j = idx - 73728;
        int c = j >> 13, rem = j & 8191;
        int n = rem >> 5, k = rem & 31;
        B2t[j] = f2bf(W2[(c * 32 + k) * 256 + n]);
    } else if (idx < 139520) {
        int n = idx - 139264;
        bias1[n] = b_agg[n] + b1[n];
    } else if (idx < 139776) {
        int n = idx - 139520;
        bias2[n] = b2[n];
    }
}

// ---------------------------------------------------------------------------
// Fused MFMA kernel:
//   rst = LRELU( feat@W1 + h@Wagg + bias1 )   [GEMM1, K=288 via bf16 MFMA]
//   out = rst@W2 + bias2                      [GEMM2, K=256, rst stays in LDS]
// Block: 64 rows x 256 cols, 4 waves; wave w covers cols [w*64, w*64+64).
// ---------------------------------------------------------------------------
#define ASTRIDE 296   // 288 K + 8 pad (bf16) -> 2-way (free) LDS conflicts

__global__ __launch_bounds__(256, 2) void k_fused_apply(
    const float* __restrict__ feat, const float* __restrict__ h_t,
    const unsigned short* __restrict__ B1t,
    const unsigned short* __restrict__ B2t,
    const float* __restrict__ bias1, const float* __restrict__ bias2,
    float* __restrict__ out, int N)
{
    __shared__ __align__(16) unsigned short As[64 * ASTRIDE];
    __shared__ __align__(16) unsigned short Bs[8192];

    int tid = threadIdx.x;
    int row0 = blockIdx.x * 64;

    // ---- Stage A: feat rows -> bf16 (cols 0..255) ----
#pragma unroll
    for (int t = 0; t < 16; ++t) {
        int i = tid + t * 256;          // 4096 = 64 rows * 64 float4
        int r = i >> 6, k4 = i & 63;
        float4 f = make_float4(0.f, 0.f, 0.f, 0.f);
        if (row0 + r < N)
            f = ((const float4*)(feat + (size_t)(row0 + r) * 256))[k4];
        ushort4 b;
        b.x = f2bf(f.x); b.y = f2bf(f.y); b.z = f2bf(f.z); b.w = f2bf(f.w);
        *(ushort4*)&As[r * ASTRIDE + k4 * 4] = b;
    }
    // ---- Stage h into cols 256..263, zeros into 264..287 ----
#pragma unroll
    for (int t = 0; t < 8; ++t) {
        int e = tid + t * 256;          // 2048 = 64 rows * 32 cols
        int r = e >> 5, c = e & 31;
        float v = 0.f;
        if (c < 8 && row0 + r < N) v = h_t[(size_t)(row0 + r) * 8 + c];
        As[r * ASTRIDE + 256 + c] = f2bf(v);
    }

    int wave = tid >> 6;
    int lane = tid & 63;
    int n16  = lane & 15;
    int quad = lane >> 4;
    int col0 = wave * 64;

    f32x4 acc[4][4];
#pragma unroll
    for (int rt = 0; rt < 4; ++rt)
#pragma unroll
        for (int ct = 0; ct < 4; ++ct)
            acc[rt][ct] = (f32x4){0.f, 0.f, 0.f, 0.f};

    // ================= GEMM1: K = 288 (9 chunks) =================
    for (int kc = 0; kc < 9; ++kc) {
        __syncthreads();
#pragma unroll
        for (int t = 0; t < 4; ++t) {
            int i = tid + t * 256;
            ((float4*)Bs)[i] = ((const float4*)(B1t + kc * 8192))[i];
        }
        __syncthreads();
        int kbase = kc * 32;
        short8 af[4], bf[4];
#pragma unroll
        for (int rt = 0; rt < 4; ++rt)
            af[rt] = *(const short8*)&As[(rt * 16 + n16) * ASTRIDE + kbase + quad * 8];
#pragma unroll
        for (int ct = 0; ct < 4; ++ct)
            bf[ct] = *(const short8*)&Bs[(col0 + ct * 16 + n16) * 32 + quad * 8];
#pragma unroll
        for (int rt = 0; rt < 4; ++rt)
#pragma unroll
            for (int ct = 0; ct < 4; ++ct)
                acc[rt][ct] = __builtin_amdgcn_mfma_f32_16x16x32_bf16(
                    af[rt], bf[ct], acc[rt][ct], 0, 0, 0);
    }

    // ---- Epilogue 1: bias + leaky, scatter rst back into As as bf16 ----
    float bi[4];
#pragma unroll
    for (int ct = 0; ct < 4; ++ct) bi[ct] = bias1[col0 + ct * 16 + n16];
    __syncthreads();   // all As reads done before overwrite
#pragma unroll
    for (int rt = 0; rt < 4; ++rt)
#pragma unroll
        for (int ct = 0; ct < 4; ++ct)
#pragma unroll
            for (int r = 0; r < 4; ++r) {
                float v = acc[rt][ct][r] + bi[ct];
                v = LRELU(v);
                int row = rt * 16 + quad * 4 + r;
                int col = col0 + ct * 16 + n16;
                As[row * ASTRIDE + col] = f2bf(v);
            }

    // ================= GEMM2: K = 256 (8 chunks) =================
#pragma unroll
    for (int rt = 0; rt < 4; ++rt)
#pragma unroll
        for (int ct = 0; ct < 4; ++ct)
            acc[rt][ct] = (f32x4){0.f, 0.f, 0.f, 0.f};

    for (int kc = 0; kc < 8; ++kc) {
        __syncthreads();
#pragma unroll
        for (int t = 0; t < 4; ++t) {
            int i = tid + t * 256;
            ((float4*)Bs)[i] = ((const float4*)(B2t + kc * 8192))[i];
        }
        __syncthreads();
        int kbase = kc * 32;
        short8 af[4], bf[4];
#pragma unroll
        for (int rt = 0; rt < 4; ++rt)
            af[rt] = *(const short8*)&As[(rt * 16 + n16) * ASTRIDE + kbase + quad * 8];
#pragma unroll
        for (int ct = 0; ct < 4; ++ct)
            bf[ct] = *(const short8*)&Bs[(col0 + ct * 16 + n16) * 32 + quad * 8];
#pragma unroll
        for (int rt = 0; rt < 4; ++rt)
#pragma unroll
            for (int ct = 0; ct < 4; ++ct)
                acc[rt][ct] = __builtin_amdgcn_mfma_f32_16x16x32_bf16(
                    af[rt], bf[ct], acc[rt][ct], 0, 0, 0);
    }

    // ---- Epilogue 2: bias2, store fp32 ----
    float bi2[4];
#pragma unroll
    for (int ct = 0; ct < 4; ++ct) bi2[ct] = bias2[col0 + ct * 16 + n16];
#pragma unroll
    for (int rt = 0; rt < 4; ++rt)
#pragma unroll
        for (int r = 0; r < 4; ++r) {
            int row = row0 + rt * 16 + quad * 4 + r;
            if (row < N) {
#pragma unroll
                for (int ct = 0; ct < 4; ++ct) {
                    int col = col0 + ct * 16 + n16;
                    out[(size_t)row * 256 + col] = acc[rt][ct][r] + bi2[ct];
                }
            }
        }
}

// ---------------------------------------------------------------------------
extern "C" void kernel_launch(void* const* d_in, const int* in_sizes, int n_in,
                              void* d_out, int out_size, void* d_ws, size_t ws_size,
                              hipStream_t stream)
{
    const float* feat      = (const float*)d_in[0];
    const float* feat_edge = (const float*)d_in[1];
    const int*   src       = (const int*)d_in[2];
    const int*   dst       = (const int*)d_in[3];
    const float* W_prop    = (const float*)d_in[4];
    const float* W_as      = (const float*)d_in[5];
    const float* W_ad      = (const float*)d_in[6];
    const float* W_edge    = (const float*)d_in[7];
    const float* bn_gamma  = (const float*)d_in[8];
    const float* bn_beta   = (const float*)d_in[9];
    const float* W_agg     = (const float*)d_in[10];
    const float* b_agg     = (const float*)d_in[11];
    const float* W1        = (const float*)d_in[12];
    const float* b1        = (const float*)d_in[13];
    const float* W2        = (const float*)d_in[14];
    const float* b2        = (const float*)d_in[15];
    float* out = (float*)d_out;

    int N = in_sizes[0] / 256;
    int E = in_sizes[2];
    int N8 = N * 8;

    // Workspace (floats): [sum_dst N8][sum_src N8][msg N8][accum 16]
    //                     [fc N8][as N8][ad N8][h N8][bias1 256][bias2 256]
    //                     then bf16: [B1t 73728][B2t 65536]
    float* ws       = (float*)d_ws;
    float* sum_dst  = ws;
    float* sum_src  = sum_dst + N8;
    float* msg      = sum_src + N8;
    float* accum    = msg + N8;
    float* fc       = accum + 16;
    float* as_t     = fc + N8;
    float* ad_t     = as_t + N8;
    float* h_t      = ad_t + N8;
    float* bias1    = h_t + N8;
    float* bias2    = bias1 + 256;
    unsigned short* B1t = (unsigned short*)(bias2 + 256);
    unsigned short* B2t = B1t + 73728;

    hipMemsetAsync(d_ws, 0, (size_t)(3 * N8 + 16) * sizeof(float), stream);

    int gridN8 = (N8 + 255) / 256;
    int gridE8 = (E * 8 + 255) / 256;
    int gridF  = (N + 63) / 64;

    k_prep<<<546, 256, 0, stream>>>(W1, W_agg, W2, b_agg, b1, b2,
                                    B1t, B2t, bias1, bias2);
    k_node_tables<<<gridN8, 256, 0, stream>>>(feat, W_prop, W_as, W_ad,
                                              fc, as_t, ad_t, N);
    k_edge1<<<gridE8, 256, 0, stream>>>(feat_edge, src, dst, W_edge,
                                        as_t, ad_t, sum_dst, sum_src, E);
    k_edge2<<<gridE8, 256, 0, stream>>>(feat_edge, src, dst, W_edge,
                                        as_t, ad_t, sum_dst, sum_src,
                                        fc, msg, E);
    k_bn_stats<<<512, 256, 0, stream>>>(msg, accum, N);
    k_bn_apply<<<gridN8, 256, 0, stream>>>(msg, accum, bn_gamma, bn_beta, h_t, N);
    k_fused_apply<<<gridF, 256, 0, stream>>>(feat, h_t, B1t, B2t,
                                             bias1, bias2, out, N);
}